// Round 3
// baseline (122.003 us; speedup 1.0000x reference)
//
#include <hip/hip_runtime.h>

// LinearAttention collapsed:
//   dots[m,h] = sum_{d in head h} (X@Wk^T)*(X@Wv^T)   [dual GEMM, 4-phase/tile schedule]
//   qsum = X @ Wqs^T ; dotb = X @ CB^T                 [side GEMM folded in as extra blocks]
//   cum = cumsum_s((dots + dotb + dbc)*mask^2); coef = cum*(qsum+bqs)
//   out = coef @ WosT + bo ; state[b,h,:,:] = cum[b, S-1, h]

typedef __attribute__((ext_vector_type(4))) float f32x4;
typedef __attribute__((ext_vector_type(8))) short bf16x8;
typedef __attribute__((ext_vector_type(8))) unsigned short u16x8;
typedef unsigned int u32;

#define GLDS16(g, l)                                                            \
  __builtin_amdgcn_global_load_lds((const __attribute__((address_space(1))) u32*)(g), \
                                   (__attribute__((address_space(3))) u32*)(l), 16, 0, 0)
#define MFMA16(a, b, c) __builtin_amdgcn_mfma_f32_16x16x32_bf16(a, b, c, 0, 0, 0)
#define PH_BAR __builtin_amdgcn_s_barrier()
#define LGK0 do { asm volatile("s_waitcnt lgkmcnt(0)" ::: "memory"); \
                  __builtin_amdgcn_sched_barrier(0); } while (0)

__device__ __forceinline__ unsigned short f2bf(float f) {
  union { float f; u32 u; } x; x.f = f;
  u32 r = (x.u + 0x7fffu + ((x.u >> 16) & 1u)) >> 16;
  return (unsigned short)r;
}

// ---------------- fused prep: Wk/Wv->bf16, weight sums, X->bf16 ----------------
__global__ void k_prep(const float* __restrict__ X, unsigned short* __restrict__ Xb,
                       const float* __restrict__ Wq, const float* __restrict__ bq,
                       const float* __restrict__ Wk, const float* __restrict__ bk,
                       const float* __restrict__ Wv, const float* __restrict__ bv,
                       const float* __restrict__ Wo,
                       unsigned short* __restrict__ Wkb, unsigned short* __restrict__ Wvb,
                       unsigned short* __restrict__ SWb, float* __restrict__ WosT,
                       float* __restrict__ scal) {
  int blk = blockIdx.x, t = threadIdx.x;
  if (blk < 2048) {                    // Wk/Wv convert
    const float* src = (blk < 1024) ? Wk : Wv;
    unsigned short* dst = (blk < 1024) ? Wkb : Wvb;
    size_t i = ((size_t)(blk & 1023) * 256 + t) * 4;
    f32x4 v = *(const f32x4*)(src + i);
    dst[i + 0] = f2bf(v.x); dst[i + 1] = f2bf(v.y);
    dst[i + 2] = f2bf(v.z); dst[i + 3] = f2bf(v.w);
  } else if (blk < 2241) {             // weight sums
    int b2 = blk - 2048;
    if (b2 < 128) {
      int o = b2 * 256 + t;
      int r = o >> 10, c = o & 1023;
      float s = 0.f;
      if (r < 16) {
        for (int d = 0; d < 64; ++d) s += Wq[(size_t)(r * 64 + d) * 1024 + c];
      } else {
        int h = r - 16;
        for (int d = 0; d < 64; ++d) {
          int j = h * 64 + d;
          s += bv[j] * Wk[(size_t)j * 1024 + c] + bk[j] * Wv[(size_t)j * 1024 + c];
        }
      }
      SWb[o] = f2bf(s);
    } else if (b2 < 192) {
      int o = (b2 - 128) * 256 + t;
      int h = o >> 10, j = o & 1023;
      float s = 0.f;
      for (int d = 0; d < 64; ++d) s += Wo[(size_t)j * 1024 + h * 64 + d];
      WosT[o] = s;
    } else {
      if (t < 16) {
        float s = 0.f;
        for (int d = 0; d < 64; ++d) s += bq[t * 64 + d];
        scal[t] = s;
      } else if (t < 32) {
        int h = t - 16;
        float s = 0.f;
        for (int d = 0; d < 64; ++d) s += bk[h * 64 + d] * bv[h * 64 + d];
        scal[t] = s;
      }
    }
  } else {                             // X convert
    size_t i = ((size_t)(blk - 2241) * 256 + t) * 8;
    f32x4 a = *(const f32x4*)(X + i);
    f32x4 b = *(const f32x4*)(X + i + 4);
    u16x8 o;
    o[0] = f2bf(a.x); o[1] = f2bf(a.y); o[2] = f2bf(a.z); o[3] = f2bf(a.w);
    o[4] = f2bf(b.x); o[5] = f2bf(b.y); o[6] = f2bf(b.z); o[7] = f2bf(b.w);
    *(u16x8*)(Xb + i) = o;
  }
}

// ---------------- dual GEMM, 4-phase/tile + folded side GEMM ----------------
// blocks 0..511: BM=256, BN=128, BK=32, 8 waves (4M x 2N), 4 LDS buffers, prefetch 3.
// blocks 512..767: side GEMM X @ SWb^T (N=32), K-split 4.
#define NT 32
__global__ __launch_bounds__(512, 2) void k_dualgemm(
    const unsigned short* __restrict__ Xb,
    const unsigned short* __restrict__ Wkb,
    const unsigned short* __restrict__ Wvb,
    const unsigned short* __restrict__ SWb,
    float* __restrict__ dotsT, float* __restrict__ side4) {
  extern __shared__ __align__(16) unsigned short lds[];  // 128 KiB
  int orig = blockIdx.x;
  int tid = threadIdx.x, wid = tid >> 6, lane = tid & 63;
  int fr = lane & 15, fg = lane >> 4;

  if (orig >= 512) {   // ---------------- side path ----------------
    int unit = orig - 512;
    int rowblk = unit >> 2, ks = unit & 3;
    int row0 = rowblk << 8;
    unsigned short* As = lds;           // 8192 elems
    unsigned short* Ss = lds + 8192;    // 1024 elems
    int uA0 = tid, uA1 = tid + 512;
    const unsigned short* sA0 = Xb + (size_t)(row0 + (uA0 >> 2)) * 1024 + ks * 256 + (((uA0 & 3) ^ ((uA0 >> 3) & 3)) << 3);
    const unsigned short* sA1 = Xb + (size_t)(row0 + (uA1 >> 2)) * 1024 + ks * 256 + (((uA1 & 3) ^ ((uA1 >> 3) & 3)) << 3);
    int uS = ((wid & 1) << 6) + lane;
    const unsigned short* sS = SWb + (size_t)(uS >> 2) * 1024 + ks * 256 + (((uS & 3) ^ ((uS >> 3) & 3)) << 3);
    int xsw = (fg ^ ((fr >> 1) & 3)) << 3;
    int aro = (wid * 32 + fr) * 32 + xsw;
    int sro = fr * 32 + xsw;
    f32x4 acc[2][2] = {{0}};
    for (int t = 0; t < 8; ++t) {
      int ko = t << 5;
      __syncthreads();
      GLDS16(sA0 + ko, As + (wid << 9));
      GLDS16(sA1 + ko, As + 4096 + (wid << 9));
      GLDS16(sS + ko, Ss + ((wid & 1) << 9));
      asm volatile("s_waitcnt vmcnt(0)" ::: "memory");
      __syncthreads();
      bf16x8 a0 = *(const bf16x8*)(As + aro);
      bf16x8 a1 = *(const bf16x8*)(As + aro + 512);
      bf16x8 s0 = *(const bf16x8*)(Ss + sro);
      bf16x8 s1 = *(const bf16x8*)(Ss + sro + 512);
      acc[0][0] = MFMA16(a0, s0, acc[0][0]);
      acc[0][1] = MFMA16(a0, s1, acc[0][1]);
      acc[1][0] = MFMA16(a1, s0, acc[1][0]);
      acc[1][1] = MFMA16(a1, s1, acc[1][1]);
    }
    size_t mbase = row0 + wid * 32;
#pragma unroll
    for (int mi = 0; mi < 2; ++mi)
#pragma unroll
      for (int ni = 0; ni < 2; ++ni)
#pragma unroll
        for (int q = 0; q < 4; ++q)
          side4[(size_t)((ni * 4 + ks) * 16 + fr) * 16384 + mbase + mi * 16 + fg * 4 + q] =
              acc[mi][ni][q];
    return;
  }

  // ---------------- dual path ----------------
  int wg = (orig & 7) * 64 + (orig >> 3);    // XCD-chunked swizzle (512 % 8 == 0)
  int bx = wg & 7, by = wg >> 3;
  int row0 = by << 8, col0 = bx << 7;
  int wrM = wid >> 1, wcN = wid & 1;

  int uA0 = tid, uA1 = tid + 512;
  const unsigned short* sA0 = Xb + (size_t)(row0 + (uA0 >> 2)) * 1024 + (((uA0 & 3) ^ ((uA0 >> 3) & 3)) << 3);
  const unsigned short* sA1 = Xb + (size_t)(row0 + (uA1 >> 2)) * 1024 + (((uA1 & 3) ^ ((uA1 >> 3) & 3)) << 3);
  const unsigned short* sK  = Wkb + (size_t)(col0 + (tid >> 2)) * 1024 + (((tid & 3) ^ ((tid >> 3) & 3)) << 3);
  const unsigned short* sV  = Wvb + (size_t)(col0 + (tid >> 2)) * 1024 + (((tid & 3) ^ ((tid >> 3) & 3)) << 3);
  int dA0 = wid << 9, dA1 = 4096 + (wid << 9);
  int dK = 8192 + (wid << 9), dV = 12288 + (wid << 9);

  int xsw = (fg ^ ((fr >> 1) & 3)) << 3;
  int aro = (wrM * 64 + fr) * 32 + xsw;   // + mi*512
  int bro = (wcN * 64 + fr) * 32 + xsw;   // + ni*512 (+8192 Bk, +12288 Bv)

  f32x4 ck[4][4] = {{0}}, cv[4][4] = {{0}};

  // prologue: stage tiles 0,1,2
#pragma unroll
  for (int p = 0; p < 3; ++p) {
    int bb = p * 16384, ko = p * 32;
    GLDS16(sA0 + ko, lds + bb + dA0);
    GLDS16(sK + ko, lds + bb + dK);
    GLDS16(sA1 + ko, lds + bb + dA1);
    GLDS16(sV + ko, lds + bb + dV);
  }
  asm volatile("s_waitcnt vmcnt(8)" ::: "memory");
  PH_BAR;

  for (int t = 0; t < NT; ++t) {
    const int rb = (t & 3) << 14;
    const int t3 = t + 3;
    const int bb = (t3 & 3) << 14;
    const int ko = t3 << 5;
    const bool st = (t3 < NT);
    bf16x8 a[4], bk[4], bv[4];

    // ---- ph0: A frags + Bk[0,1] -> ck[*][0..1]
#pragma unroll
    for (int mi = 0; mi < 4; ++mi) a[mi] = *(const bf16x8*)(lds + rb + aro + mi * 512);
    bk[0] = *(const bf16x8*)(lds + rb + 8192 + bro);
    bk[1] = *(const bf16x8*)(lds + rb + 8192 + bro + 512);
    if (st) GLDS16(sA0 + ko, lds + bb + dA0);
    PH_BAR; LGK0;
    __builtin_amdgcn_s_setprio(1);
#pragma unroll
    for (int mi = 0; mi < 4; ++mi) {
      ck[mi][0] = MFMA16(a[mi], bk[0], ck[mi][0]);
      ck[mi][1] = MFMA16(a[mi], bk[1], ck[mi][1]);
    }
    __builtin_amdgcn_s_setprio(0);
    PH_BAR;

    // ---- ph1: Bv[0,1] -> cv[*][0..1]
    bv[0] = *(const bf16x8*)(lds + rb + 12288 + bro);
    bv[1] = *(const bf16x8*)(lds + rb + 12288 + bro + 512);
    if (st) GLDS16(sK + ko, lds + bb + dK);
    PH_BAR; LGK0;
    __builtin_amdgcn_s_setprio(1);
#pragma unroll
    for (int mi = 0; mi < 4; ++mi) {
      cv[mi][0] = MFMA16(a[mi], bv[0], cv[mi][0]);
      cv[mi][1] = MFMA16(a[mi], bv[1], cv[mi][1]);
    }
    __builtin_amdgcn_s_setprio(0);
    PH_BAR;

    // ---- ph2: Bk[2,3] -> ck[*][2..3]
    bk[2] = *(const bf16x8*)(lds + rb + 8192 + bro + 1024);
    bk[3] = *(const bf16x8*)(lds + rb + 8192 + bro + 1536);
    if (st) GLDS16(sA1 + ko, lds + bb + dA1);
    PH_BAR; LGK0;
    __builtin_amdgcn_s_setprio(1);
#pragma unroll
    for (int mi = 0; mi < 4; ++mi) {
      ck[mi][2] = MFMA16(a[mi], bk[2], ck[mi][2]);
      ck[mi][3] = MFMA16(a[mi], bk[3], ck[mi][3]);
    }
    __builtin_amdgcn_s_setprio(0);
    PH_BAR;

    // ---- ph3: Bv[2,3] -> cv[*][2..3]
    bv[2] = *(const bf16x8*)(lds + rb + 12288 + bro + 1024);
    bv[3] = *(const bf16x8*)(lds + rb + 12288 + bro + 1536);
    if (st) GLDS16(sV + ko, lds + bb + dV);
    PH_BAR; LGK0;
    __builtin_amdgcn_s_setprio(1);
#pragma unroll
    for (int mi = 0; mi < 4; ++mi) {
      cv[mi][2] = MFMA16(a[mi], bv[2], cv[mi][2]);
      cv[mi][3] = MFMA16(a[mi], bv[3], cv[mi][3]);
    }
    __builtin_amdgcn_s_setprio(0);
    // tile boundary: counted vmcnt (never 0 until drain)
    if (t <= NT - 4)      { asm volatile("s_waitcnt vmcnt(8)" ::: "memory"); }
    else if (t == NT - 3) { asm volatile("s_waitcnt vmcnt(4)" ::: "memory"); }
    else                  { asm volatile("s_waitcnt vmcnt(0)" ::: "memory"); }
    PH_BAR;
  }

  // epilogue: dots = per-head sum over 64 cols of ck*cv
  float part[4][4];
#pragma unroll
  for (int mi = 0; mi < 4; ++mi)
#pragma unroll
    for (int q = 0; q < 4; ++q) {
      float s = 0.f;
#pragma unroll
      for (int ni = 0; ni < 4; ++ni) s += ck[mi][ni][q] * cv[mi][ni][q];
      part[mi][q] = s;
    }
#pragma unroll
  for (int r = 0; r < 4; ++r) {
#pragma unroll
    for (int mi = 0; mi < 4; ++mi)
#pragma unroll
      for (int q = 0; q < 4; ++q)
        part[mi][q] += __shfl_xor(part[mi][q], 1 << r, 64);
  }
  int h = bx * 2 + wcN;
  if (fr == 0) {
#pragma unroll
    for (int mi = 0; mi < 4; ++mi)
#pragma unroll
      for (int q = 0; q < 4; ++q)
        dotsT[(size_t)h * 16384 + row0 + wrM * 64 + mi * 16 + fg * 4 + q] = part[mi][q];
  }
}

// ---------------- cumsum + coef + state ----------------
__global__ void k_cumsum(const float* __restrict__ dotsT, const float* __restrict__ side4,
                         const float* __restrict__ scal, const float* __restrict__ mask,
                         float* __restrict__ coef, float* __restrict__ state) {
  __shared__ float csum[256];
  int b = blockIdx.x >> 4, h = blockIdx.x & 15;
  int t = threadIdx.x;
  float bqs = scal[h], dbc = scal[16 + h];
  size_t m0 = (size_t)b * 4096;
  const size_t KSS = (size_t)16 * 16384;
  const float* dro = dotsT + (size_t)h * 16384 + m0;
  const float* qb = side4 + (size_t)h * 16384 + m0;
  const float* db = side4 + 4 * KSS + (size_t)h * 16384 + m0;
  const float* mko = mask + m0;
  float loc[16], run = 0.f;
  int s0 = t * 16;
#pragma unroll
  for (int i = 0; i < 16; ++i) {
    int ii = s0 + i;
    float mk = mko[ii];
    float dball = db[ii] + db[ii + KSS] + db[ii + 2 * KSS] + db[ii + 3 * KSS];
    float d = (dro[ii] + dball + dbc) * mk * mk;
    run += d;
    loc[i] = run;
  }
  csum[t] = run;
  __syncthreads();
  for (int off = 1; off < 256; off <<= 1) {
    float v = (t >= off) ? csum[t - off] : 0.f;
    __syncthreads();
    csum[t] += v;
    __syncthreads();
  }
  float prefix = csum[t] - run;
#pragma unroll
  for (int i = 0; i < 16; ++i) {
    int ii = s0 + i;
    float cum = prefix + loc[i];
    float qs = qb[ii] + qb[ii + KSS] + qb[ii + 2 * KSS] + qb[ii + 3 * KSS];
    coef[(m0 + ii) * 16 + h] = cum * (qs + bqs);
  }
  float total = csum[255];
  float* sp = state + (size_t)(b * 16 + h) * 4096;
  for (int i = t; i < 4096; i += 256) sp[i] = total;
}

// ---------------- output GEMM: out = coef(16384x16) @ WosT(16x1024) + bo ----------------
__global__ __launch_bounds__(256) void k_outgemm(const float* __restrict__ coef,
                                                 const float* __restrict__ WosT,
                                                 const float* __restrict__ bo,
                                                 float* __restrict__ out) {
  int t = threadIdx.x;
  int j0 = t * 4;
  f32x4 w4[16];
#pragma unroll
  for (int hh = 0; hh < 16; ++hh) w4[hh] = *(const f32x4*)&WosT[hh * 1024 + j0];
  f32x4 bov = *(const f32x4*)&bo[j0];
  size_t m0 = (size_t)blockIdx.x * 32;
  for (int mi = 0; mi < 32; ++mi) {
    size_t m = m0 + mi;
    const float* cm = &coef[m * 16];
    f32x4 acc = bov;
#pragma unroll
    for (int hh = 0; hh < 16; ++hh) acc += w4[hh] * cm[hh];
    *(f32x4*)&out[m * 1024 + j0] = acc;
  }
}

extern "C" void kernel_launch(void* const* d_in, const int* in_sizes, int n_in,
                              void* d_out, int out_size, void* d_ws, size_t ws_size,
                              hipStream_t stream) {
  const float* X    = (const float*)d_in[0];
  const float* mask = (const float*)d_in[1];
  const float* Wq   = (const float*)d_in[2];
  const float* bq   = (const float*)d_in[3];
  const float* Wk   = (const float*)d_in[4];
  const float* bk   = (const float*)d_in[5];
  const float* Wv   = (const float*)d_in[6];
  const float* bv   = (const float*)d_in[7];
  const float* Wo   = (const float*)d_in[8];
  const float* bo   = (const float*)d_in[9];
  float* out   = (float*)d_out;
  float* state = out + (size_t)16384 * 1024;

  char* w = (char*)d_ws;
  unsigned short* Xb  = (unsigned short*)w; w += (size_t)16384 * 1024 * 2;
  unsigned short* Wkb = (unsigned short*)w; w += (size_t)1024 * 1024 * 2;
  unsigned short* Wvb = (unsigned short*)w; w += (size_t)1024 * 1024 * 2;
  unsigned short* SWb = (unsigned short*)w; w += (size_t)32 * 1024 * 2;
  float* WosT  = (float*)w; w += (size_t)16 * 1024 * 4;
  float* scal  = (float*)w; w += 256;
  float* dotsT = (float*)w; w += (size_t)16 * 16384 * 4;
  float* side4 = (float*)w; w += (size_t)8 * 16 * 16384 * 4;
  float* coef  = (float*)w; w += (size_t)16384 * 16 * 4;

  (void)hipFuncSetAttribute((const void*)k_dualgemm,
                            hipFuncAttributeMaxDynamicSharedMemorySize, 131072);

  hipLaunchKernelGGL(k_prep,     dim3(10433), dim3(256), 0, stream,
                     X, Xb, Wq, bq, Wk, bk, Wv, bv, Wo, Wkb, Wvb, SWb, WosT, scal);
  hipLaunchKernelGGL(k_dualgemm, dim3(768),  dim3(512), 131072, stream, Xb, Wkb, Wvb, SWb,
                     dotsT, side4);
  hipLaunchKernelGGL(k_cumsum,   dim3(64),   dim3(256), 0, stream, dotsT, side4, scal,
                     mask, coef, state);
  hipLaunchKernelGGL(k_outgemm,  dim3(512),  dim3(256), 0, stream, coef, WosT, bo, out);
}

// Round 4
// 116.085 us; speedup vs baseline: 1.0510x; 1.0510x over previous
//
#include <hip/hip_runtime.h>

// LinearAttention collapsed:
//   dots[m,h] = sum_{d in head h} (X@Wk^T)*(X@Wv^T)   [dual GEMM, 2x16-MFMA phases/tile]
//   qsum = X @ Wqs^T ; dotb = X @ CB^T                 [piggybacked on bx==0 blocks]
//   cum = cumsum_s((dots + dotb + dbc)*mask^2); coef = cum*(qsum+bqs)
//   out = coef @ WosT + bo ; state[b,h,:,:] = cum[b, S-1, h]

typedef __attribute__((ext_vector_type(4))) float f32x4;
typedef __attribute__((ext_vector_type(8))) short bf16x8;
typedef __attribute__((ext_vector_type(8))) unsigned short u16x8;
typedef unsigned int u32;

#define GLDS16(g, l)                                                            \
  __builtin_amdgcn_global_load_lds((const __attribute__((address_space(1))) u32*)(g), \
                                   (__attribute__((address_space(3))) u32*)(l), 16, 0, 0)
#define MFMA16(a, b, c) __builtin_amdgcn_mfma_f32_16x16x32_bf16(a, b, c, 0, 0, 0)
#define PH_BAR __builtin_amdgcn_s_barrier()
#define LGK0 do { asm volatile("s_waitcnt lgkmcnt(0)" ::: "memory"); \
                  __builtin_amdgcn_sched_barrier(0); } while (0)

__device__ __forceinline__ unsigned short f2bf(float f) {
  union { float f; u32 u; } x; x.f = f;
  u32 r = (x.u + 0x7fffu + ((x.u >> 16) & 1u)) >> 16;
  return (unsigned short)r;
}

// ---------------- fused prep: Wk/Wv->bf16, weight sums, X->bf16 ----------------
__global__ void k_prep(const float* __restrict__ X, unsigned short* __restrict__ Xb,
                       const float* __restrict__ Wq, const float* __restrict__ bq,
                       const float* __restrict__ Wk, const float* __restrict__ bk,
                       const float* __restrict__ Wv, const float* __restrict__ bv,
                       const float* __restrict__ Wo,
                       unsigned short* __restrict__ Wkb, unsigned short* __restrict__ Wvb,
                       unsigned short* __restrict__ SWb, float* __restrict__ WosT,
                       float* __restrict__ scal) {
  int blk = blockIdx.x, t = threadIdx.x;
  if (blk < 2048) {                    // Wk/Wv convert
    const float* src = (blk < 1024) ? Wk : Wv;
    unsigned short* dst = (blk < 1024) ? Wkb : Wvb;
    size_t i = ((size_t)(blk & 1023) * 256 + t) * 4;
    f32x4 v = *(const f32x4*)(src + i);
    dst[i + 0] = f2bf(v.x); dst[i + 1] = f2bf(v.y);
    dst[i + 2] = f2bf(v.z); dst[i + 3] = f2bf(v.w);
  } else if (blk < 2241) {             // weight sums
    int b2 = blk - 2048;
    if (b2 < 128) {
      int o = b2 * 256 + t;
      int r = o >> 10, c = o & 1023;
      float s = 0.f;
      if (r < 16) {
        for (int d = 0; d < 64; ++d) s += Wq[(size_t)(r * 64 + d) * 1024 + c];
      } else {
        int h = r - 16;
        for (int d = 0; d < 64; ++d) {
          int j = h * 64 + d;
          s += bv[j] * Wk[(size_t)j * 1024 + c] + bk[j] * Wv[(size_t)j * 1024 + c];
        }
      }
      SWb[o] = f2bf(s);
    } else if (b2 < 192) {
      int o = (b2 - 128) * 256 + t;
      int h = o >> 10, j = o & 1023;
      float s = 0.f;
      for (int d = 0; d < 64; ++d) s += Wo[(size_t)j * 1024 + h * 64 + d];
      WosT[o] = s;
    } else {
      if (t < 16) {
        float s = 0.f;
        for (int d = 0; d < 64; ++d) s += bq[t * 64 + d];
        scal[t] = s;
      } else if (t < 32) {
        int h = t - 16;
        float s = 0.f;
        for (int d = 0; d < 64; ++d) s += bk[h * 64 + d] * bv[h * 64 + d];
        scal[t] = s;
      }
    }
  } else {                             // X convert
    size_t i = ((size_t)(blk - 2241) * 256 + t) * 8;
    f32x4 a = *(const f32x4*)(X + i);
    f32x4 b = *(const f32x4*)(X + i + 4);
    u16x8 o;
    o[0] = f2bf(a.x); o[1] = f2bf(a.y); o[2] = f2bf(a.z); o[3] = f2bf(a.w);
    o[4] = f2bf(b.x); o[5] = f2bf(b.y); o[6] = f2bf(b.z); o[7] = f2bf(b.w);
    *(u16x8*)(Xb + i) = o;
  }
}

// ---------------- dual GEMM, 2-phase/tile (16 MFMA each) + piggybacked side ----------------
// BM=256, BN=128, BK=32, 8 waves (4M x 2N), 4 LDS buffers, prefetch depth 3.
// Buffer layout (elems): A @0 (8192), Bk @8192 (4096), Bv @12288 (4096), SW @16384 (1024).
// Buffer stride 17408 elems; 4 buffers = 139264 B dynamic LDS.
#define NT 32
#define BUFS 17408
__global__ __launch_bounds__(512, 1) void k_dualgemm(
    const unsigned short* __restrict__ Xb,
    const unsigned short* __restrict__ Wkb,
    const unsigned short* __restrict__ Wvb,
    const unsigned short* __restrict__ SWb,
    float* __restrict__ dotsT, float* __restrict__ qsumT, float* __restrict__ dotbT) {
  extern __shared__ __align__(16) unsigned short lds[];
  int orig = blockIdx.x;
  int wg = (orig & 7) * 64 + (orig >> 3);    // XCD-chunked swizzle (512 % 8 == 0)
  int bx = wg & 7, by = wg >> 3;
  int row0 = by << 8, col0 = bx << 7;
  int tid = threadIdx.x, wid = tid >> 6, lane = tid & 63;
  int wrM = wid >> 1, wcN = wid & 1;
  int fr = lane & 15, fg = lane >> 4;
  bool side = (bx == 0);

  // staging sources (pre-swizzled 16B units)
  int uA0 = tid, uA1 = tid + 512;
  const unsigned short* sA0 = Xb + (size_t)(row0 + (uA0 >> 2)) * 1024 + (((uA0 & 3) ^ ((uA0 >> 3) & 3)) << 3);
  const unsigned short* sA1 = Xb + (size_t)(row0 + (uA1 >> 2)) * 1024 + (((uA1 & 3) ^ ((uA1 >> 3) & 3)) << 3);
  const unsigned short* sK  = Wkb + (size_t)(col0 + (tid >> 2)) * 1024 + (((tid & 3) ^ ((tid >> 3) & 3)) << 3);
  const unsigned short* sV  = Wvb + (size_t)(col0 + (tid >> 2)) * 1024 + (((tid & 3) ^ ((tid >> 3) & 3)) << 3);
  const unsigned short* sS  = SWb + (size_t)(tid >> 2) * 1024 + (((tid & 3) ^ ((tid >> 3) & 3)) << 3);  // tid<128
  // wave-uniform LDS dest bases (elements, within buffer)
  int dA0 = wid << 9, dA1 = 4096 + (wid << 9);
  int dK = 8192 + (wid << 9), dV = 12288 + (wid << 9);
  int dS = 16384 + (wid << 9);   // only wid<2
  bool stageSW = side && (wid < 2);

  // fragment read offsets (swizzled)
  int xsw = (fg ^ ((fr >> 1) & 3)) << 3;
  int aro = (wrM * 64 + fr) * 32 + xsw;            // + mi*512
  int bro = (wcN * 64 + fr) * 32 + xsw;            // + ni*512 (+8192 Bk, +12288 Bv)
  int swo = 16384 + (wcN * 16 + fr) * 32 + xsw;    // SW frag (wcN=0: Wqs rows, wcN=1: CB rows)

  f32x4 ck[4][4] = {{0}}, cv[4][4] = {{0}};
  f32x4 qa[4] = {0, 0, 0, 0};

  // prologue: stage tiles 0,1,2
#pragma unroll
  for (int p = 0; p < 3; ++p) {
    int bb = p * BUFS, ko = p * 32;
    GLDS16(sA0 + ko, lds + bb + dA0);
    GLDS16(sK + ko, lds + bb + dK);
    GLDS16(sA1 + ko, lds + bb + dA1);
    GLDS16(sV + ko, lds + bb + dV);
    if (stageSW) GLDS16(sS + ko, lds + bb + dS);
  }
  asm volatile("s_waitcnt vmcnt(8)" ::: "memory");
  PH_BAR;

  for (int t = 0; t < NT; ++t) {
    const int rb = (t & 3) * BUFS;
    const int t3 = t + 3;
    const int bb = (t3 & 3) * BUFS;
    const int ko = t3 << 5;
    const bool st = (t3 < NT);
    bf16x8 a[4], bk[4], bv[4];

    // ---- ph0: A frags + Bk -> ck (16 MFMA)
#pragma unroll
    for (int mi = 0; mi < 4; ++mi) a[mi] = *(const bf16x8*)(lds + rb + aro + mi * 512);
#pragma unroll
    for (int ni = 0; ni < 4; ++ni) bk[ni] = *(const bf16x8*)(lds + rb + 8192 + bro + ni * 512);
    if (st) {
      GLDS16(sA0 + ko, lds + bb + dA0);
      GLDS16(sK + ko, lds + bb + dK);
    }
    PH_BAR; LGK0;
    __builtin_amdgcn_s_setprio(1);
#pragma unroll
    for (int mi = 0; mi < 4; ++mi)
#pragma unroll
      for (int ni = 0; ni < 4; ++ni)
        ck[mi][ni] = MFMA16(a[mi], bk[ni], ck[mi][ni]);
    __builtin_amdgcn_s_setprio(0);
    PH_BAR;

    // ---- ph1: Bv (+SW) -> cv (16 MFMA) (+4 side MFMA)
#pragma unroll
    for (int ni = 0; ni < 4; ++ni) bv[ni] = *(const bf16x8*)(lds + rb + 12288 + bro + ni * 512);
    bf16x8 sw;
    if (side) sw = *(const bf16x8*)(lds + rb + swo);
    if (st) {
      GLDS16(sA1 + ko, lds + bb + dA1);
      GLDS16(sV + ko, lds + bb + dV);
      if (stageSW) GLDS16(sS + ko, lds + bb + dS);
    }
    PH_BAR; LGK0;
    __builtin_amdgcn_s_setprio(1);
#pragma unroll
    for (int mi = 0; mi < 4; ++mi)
#pragma unroll
      for (int ni = 0; ni < 4; ++ni)
        cv[mi][ni] = MFMA16(a[mi], bv[ni], cv[mi][ni]);
    if (side) {
#pragma unroll
      for (int mi = 0; mi < 4; ++mi) qa[mi] = MFMA16(a[mi], sw, qa[mi]);
    }
    __builtin_amdgcn_s_setprio(0);
    // tile boundary: counted vmcnt (never 0 until drain)
    if (t <= NT - 4)      { asm volatile("s_waitcnt vmcnt(8)" ::: "memory"); }
    else if (t == NT - 3) { asm volatile("s_waitcnt vmcnt(4)" ::: "memory"); }
    else                  { asm volatile("s_waitcnt vmcnt(0)" ::: "memory"); }
    PH_BAR;
  }

  // epilogue: dots = per-head sum over 64 cols of ck*cv
  float part[4][4];
#pragma unroll
  for (int mi = 0; mi < 4; ++mi)
#pragma unroll
    for (int q = 0; q < 4; ++q) {
      float s = 0.f;
#pragma unroll
      for (int ni = 0; ni < 4; ++ni) s += ck[mi][ni][q] * cv[mi][ni][q];
      part[mi][q] = s;
    }
#pragma unroll
  for (int r = 0; r < 4; ++r) {
#pragma unroll
    for (int mi = 0; mi < 4; ++mi)
#pragma unroll
      for (int q = 0; q < 4; ++q)
        part[mi][q] += __shfl_xor(part[mi][q], 1 << r, 64);
  }
  int h = bx * 2 + wcN;
  if (fr == 0) {
#pragma unroll
    for (int mi = 0; mi < 4; ++mi)
#pragma unroll
      for (int q = 0; q < 4; ++q)
        dotsT[(size_t)h * 16384 + row0 + wrM * 64 + mi * 16 + fg * 4 + q] = part[mi][q];
  }
  if (side) {
    float* dst = (wcN == 0) ? qsumT : dotbT;   // C/D col (lane&15) == side-head index
#pragma unroll
    for (int mi = 0; mi < 4; ++mi)
#pragma unroll
      for (int q = 0; q < 4; ++q)
        dst[(size_t)fr * 16384 + row0 + wrM * 64 + mi * 16 + fg * 4 + q] = qa[mi][q];
  }
}

// ---------------- cumsum + coef + state ----------------
__global__ void k_cumsum(const float* __restrict__ dotsT, const float* __restrict__ dotbT,
                         const float* __restrict__ qsumT, const float* __restrict__ scal,
                         const float* __restrict__ mask,
                         float* __restrict__ coef, float* __restrict__ state) {
  __shared__ float csum[256];
  int b = blockIdx.x >> 4, h = blockIdx.x & 15;
  int t = threadIdx.x;
  float bqs = scal[h], dbc = scal[16 + h];
  size_t m0 = (size_t)b * 4096;
  const float* dro = dotsT + (size_t)h * 16384 + m0;
  const float* dbo = dotbT + (size_t)h * 16384 + m0;
  const float* qso = qsumT + (size_t)h * 16384 + m0;
  const float* mko = mask + m0;
  float loc[16], run = 0.f;
  int s0 = t * 16;
#pragma unroll
  for (int i = 0; i < 16; ++i) {
    int ii = s0 + i;
    float mk = mko[ii];
    float d = (dro[ii] + dbo[ii] + dbc) * mk * mk;
    run += d;
    loc[i] = run;
  }
  csum[t] = run;
  __syncthreads();
  for (int off = 1; off < 256; off <<= 1) {
    float v = (t >= off) ? csum[t - off] : 0.f;
    __syncthreads();
    csum[t] += v;
    __syncthreads();
  }
  float prefix = csum[t] - run;
#pragma unroll
  for (int i = 0; i < 16; ++i) {
    int ii = s0 + i;
    float cum = prefix + loc[i];
    coef[(m0 + ii) * 16 + h] = cum * (qso[ii] + bqs);
  }
  float total = csum[255];
  float* sp = state + (size_t)(b * 16 + h) * 4096;
  for (int i = t; i < 4096; i += 256) sp[i] = total;
}

// ---------------- output GEMM: out = coef(16384x16) @ WosT(16x1024) + bo ----------------
__global__ __launch_bounds__(256) void k_outgemm(const float* __restrict__ coef,
                                                 const float* __restrict__ WosT,
                                                 const float* __restrict__ bo,
                                                 float* __restrict__ out) {
  int t = threadIdx.x;
  int j0 = t * 4;
  f32x4 w4[16];
#pragma unroll
  for (int hh = 0; hh < 16; ++hh) w4[hh] = *(const f32x4*)&WosT[hh * 1024 + j0];
  f32x4 bov = *(const f32x4*)&bo[j0];
  size_t m0 = (size_t)blockIdx.x * 32;
  for (int mi = 0; mi < 32; ++mi) {
    size_t m = m0 + mi;
    const float* cm = &coef[m * 16];
    f32x4 acc = bov;
#pragma unroll
    for (int hh = 0; hh < 16; ++hh) acc += w4[hh] * cm[hh];
    *(f32x4*)&out[m * 1024 + j0] = acc;
  }
}

extern "C" void kernel_launch(void* const* d_in, const int* in_sizes, int n_in,
                              void* d_out, int out_size, void* d_ws, size_t ws_size,
                              hipStream_t stream) {
  const float* X    = (const float*)d_in[0];
  const float* mask = (const float*)d_in[1];
  const float* Wq   = (const float*)d_in[2];
  const float* bq   = (const float*)d_in[3];
  const float* Wk   = (const float*)d_in[4];
  const float* bk   = (const float*)d_in[5];
  const float* Wv   = (const float*)d_in[6];
  const float* bv   = (const float*)d_in[7];
  const float* Wo   = (const float*)d_in[8];
  const float* bo   = (const float*)d_in[9];
  float* out   = (float*)d_out;
  float* state = out + (size_t)16384 * 1024;

  char* w = (char*)d_ws;
  unsigned short* Xb  = (unsigned short*)w; w += (size_t)16384 * 1024 * 2;
  unsigned short* Wkb = (unsigned short*)w; w += (size_t)1024 * 1024 * 2;
  unsigned short* Wvb = (unsigned short*)w; w += (size_t)1024 * 1024 * 2;
  unsigned short* SWb = (unsigned short*)w; w += (size_t)32 * 1024 * 2;
  float* WosT  = (float*)w; w += (size_t)16 * 1024 * 4;
  float* scal  = (float*)w; w += 256;
  float* dotsT = (float*)w; w += (size_t)16 * 16384 * 4;
  float* qsumT = (float*)w; w += (size_t)16 * 16384 * 4;
  float* dotbT = (float*)w; w += (size_t)16 * 16384 * 4;
  float* coef  = (float*)w; w += (size_t)16384 * 16 * 4;

  (void)hipFuncSetAttribute((const void*)k_dualgemm,
                            hipFuncAttributeMaxDynamicSharedMemorySize, 139264);

  hipLaunchKernelGGL(k_prep,     dim3(10433), dim3(256), 0, stream,
                     X, Xb, Wq, bq, Wk, bk, Wv, bv, Wo, Wkb, Wvb, SWb, WosT, scal);
  hipLaunchKernelGGL(k_dualgemm, dim3(512),  dim3(512), 139264, stream, Xb, Wkb, Wvb, SWb,
                     dotsT, qsumT, dotbT);
  hipLaunchKernelGGL(k_cumsum,   dim3(64),   dim3(256), 0, stream, dotsT, dotbT, qsumT, scal,
                     mask, coef, state);
  hipLaunchKernelGGL(k_outgemm,  dim3(512),  dim3(256), 0, stream, coef, WosT, bo, out);
}

// Round 5
// 107.962 us; speedup vs baseline: 1.1301x; 1.0752x over previous
//
#include <hip/hip_runtime.h>

// LinearAttention collapsed:
//   dots[m,h] = sum_{d in head h} (X@Wk^T)*(X@Wv^T)   [dual GEMM, BK=64, 1 barrier/tile]
//   qsum = X @ Wqs^T ; dotb = X @ CB^T                 [piggybacked on bx==0 blocks]
//   cum = cumsum_s((dots + dotb + dbc)*mask^2); coef = cum*(qsum+bqs)
//   out = coef @ WosT + bo ; state[b,h,:,:] = cum[b, S-1, h]

typedef __attribute__((ext_vector_type(4))) float f32x4;
typedef __attribute__((ext_vector_type(8))) short bf16x8;
typedef __attribute__((ext_vector_type(8))) unsigned short u16x8;
typedef unsigned int u32;

#define GLDS16(g, l)                                                            \
  __builtin_amdgcn_global_load_lds((const __attribute__((address_space(1))) u32*)(g), \
                                   (__attribute__((address_space(3))) u32*)(l), 16, 0, 0)
#define MFMA16(a, b, c) __builtin_amdgcn_mfma_f32_16x16x32_bf16(a, b, c, 0, 0, 0)
#define PH_BAR __builtin_amdgcn_s_barrier()
#define LGK0 do { asm volatile("s_waitcnt lgkmcnt(0)" ::: "memory"); \
                  __builtin_amdgcn_sched_barrier(0); } while (0)

__device__ __forceinline__ unsigned short f2bf(float f) {
  union { float f; u32 u; } x; x.f = f;
  u32 r = (x.u + 0x7fffu + ((x.u >> 16) & 1u)) >> 16;
  return (unsigned short)r;
}

// ---------------- fused prep: Wk/Wv->bf16, weight sums, X->bf16 ----------------
__global__ void k_prep(const float* __restrict__ X, unsigned short* __restrict__ Xb,
                       const float* __restrict__ Wq, const float* __restrict__ bq,
                       const float* __restrict__ Wk, const float* __restrict__ bk,
                       const float* __restrict__ Wv, const float* __restrict__ bv,
                       const float* __restrict__ Wo,
                       unsigned short* __restrict__ Wkb, unsigned short* __restrict__ Wvb,
                       unsigned short* __restrict__ SWb, float* __restrict__ WosT,
                       float* __restrict__ scal) {
  int blk = blockIdx.x, t = threadIdx.x;
  if (blk < 2048) {                    // Wk/Wv convert
    const float* src = (blk < 1024) ? Wk : Wv;
    unsigned short* dst = (blk < 1024) ? Wkb : Wvb;
    size_t i = ((size_t)(blk & 1023) * 256 + t) * 4;
    f32x4 v = *(const f32x4*)(src + i);
    dst[i + 0] = f2bf(v.x); dst[i + 1] = f2bf(v.y);
    dst[i + 2] = f2bf(v.z); dst[i + 3] = f2bf(v.w);
  } else if (blk < 2241) {             // weight sums
    int b2 = blk - 2048;
    if (b2 < 128) {
      int o = b2 * 256 + t;
      int r = o >> 10, c = o & 1023;
      float s = 0.f;
      if (r < 16) {
        for (int d = 0; d < 64; ++d) s += Wq[(size_t)(r * 64 + d) * 1024 + c];
      } else {
        int h = r - 16;
        for (int d = 0; d < 64; ++d) {
          int j = h * 64 + d;
          s += bv[j] * Wk[(size_t)j * 1024 + c] + bk[j] * Wv[(size_t)j * 1024 + c];
        }
      }
      SWb[o] = f2bf(s);
    } else if (b2 < 192) {
      int o = (b2 - 128) * 256 + t;
      int h = o >> 10, j = o & 1023;
      float s = 0.f;
      for (int d = 0; d < 64; ++d) s += Wo[(size_t)j * 1024 + h * 64 + d];
      WosT[o] = s;
    } else {
      if (t < 16) {
        float s = 0.f;
        for (int d = 0; d < 64; ++d) s += bq[t * 64 + d];
        scal[t] = s;
      } else if (t < 32) {
        int h = t - 16;
        float s = 0.f;
        for (int d = 0; d < 64; ++d) s += bk[h * 64 + d] * bv[h * 64 + d];
        scal[t] = s;
      }
    }
  } else {                             // X convert
    size_t i = ((size_t)(blk - 2241) * 256 + t) * 8;
    f32x4 a = *(const f32x4*)(X + i);
    f32x4 b = *(const f32x4*)(X + i + 4);
    u16x8 o;
    o[0] = f2bf(a.x); o[1] = f2bf(a.y); o[2] = f2bf(a.z); o[3] = f2bf(a.w);
    o[4] = f2bf(b.x); o[5] = f2bf(b.y); o[6] = f2bf(b.z); o[7] = f2bf(b.w);
    *(u16x8*)(Xb + i) = o;
  }
}

// ---------------- dual GEMM: BM=256, BN=128, BK=64, 8 waves (4M x 2N) ----------------
// 2 LDS buffers, depth-1 prefetch, ONE barrier + one (free) vmcnt(0) per tile.
// Buffer layout (elems): A @0 (16384), Bk @16384 (8192), Bv @24576 (8192), SW @32768 (2048).
// Buffer stride 34816 elems; 2 buffers = 139264 B dynamic LDS.
// Row = 64 bf16 = 8 x 16B units; swizzle: unit ^= (row & 7) on source and read.
#define NT 16
#define BUFS 34816
__global__ __launch_bounds__(512, 1) void k_dualgemm(
    const unsigned short* __restrict__ Xb,
    const unsigned short* __restrict__ Wkb,
    const unsigned short* __restrict__ Wvb,
    const unsigned short* __restrict__ SWb,
    float* __restrict__ dotsT, float* __restrict__ qsumT, float* __restrict__ dotbT) {
  extern __shared__ __align__(16) unsigned short lds[];
  int orig = blockIdx.x;
  int wg = (orig & 7) * 64 + (orig >> 3);    // XCD-chunked swizzle (512 % 8 == 0)
  int bx = wg & 7, by = wg >> 3;
  int row0 = by << 8, col0 = bx << 7;
  int tid = threadIdx.x, wid = tid >> 6, lane = tid & 63;
  int wrM = wid >> 1, wcN = wid & 1;
  int fr = lane & 15, fg = lane >> 4;
  bool side = (bx == 0);
  bool stageSW = side && (wid < 4);
  int dW = wid << 9;                   // wave-uniform LDS dest offset (elems)

  // staging sources (pre-swizzled 16B units). For unit U of a tile region:
  // row r = U>>3, swizzled k-unit = (U&7)^(r&7); per-tile add ko = t*64 elems.
  const unsigned short *sA[4], *sK[2], *sV[2], *sS;
#pragma unroll
  for (int c = 0; c < 4; ++c) {
    int U = c * 512 + tid, r = U >> 3;
    sA[c] = Xb + (size_t)(row0 + r) * 1024 + (((U & 7) ^ (r & 7)) << 3);
  }
#pragma unroll
  for (int c = 0; c < 2; ++c) {
    int U = c * 512 + tid, r = U >> 3;
    int usw = ((U & 7) ^ (r & 7)) << 3;
    sK[c] = Wkb + (size_t)(col0 + r) * 1024 + usw;
    sV[c] = Wvb + (size_t)(col0 + r) * 1024 + usw;
  }
  {
    int U = tid & 255, r = U >> 3;
    sS = SWb + (size_t)r * 1024 + (((U & 7) ^ (r & 7)) << 3);
  }

  // fragment read offsets (elems within buffer), kk = 0/1 adds unit 4 -> +?? via table
  int arow = wrM * 64 + fr;            // + mi*16
  int brow = wcN * 64 + fr;            // + ni*16
  int srow = wcN * 16 + fr;
  int f7 = fr & 7;
  int u0 = ((0 * 4 + fg) ^ f7) << 3;   // kk=0 swizzled unit offset (elems)
  int u1 = ((1 * 4 + fg) ^ f7) << 3;   // kk=1

  f32x4 ck[4][4] = {{0}}, cv[4][4] = {{0}};
  f32x4 qa[4] = {0, 0, 0, 0};

  // prologue: stage tile 0 -> buf0
  {
#pragma unroll
    for (int c = 0; c < 4; ++c) GLDS16(sA[c], lds + c * 4096 + dW);
#pragma unroll
    for (int c = 0; c < 2; ++c) {
      GLDS16(sK[c], lds + 16384 + c * 4096 + dW);
      GLDS16(sV[c], lds + 24576 + c * 4096 + dW);
    }
    if (stageSW) GLDS16(sS, lds + 32768 + dW);
    asm volatile("s_waitcnt vmcnt(0)" ::: "memory");
    PH_BAR;
  }

  for (int t = 0; t < NT; ++t) {
    const int rb = (t & 1) * BUFS;
    const int wb = ((t + 1) & 1) * BUFS;
    const int ko = (t + 1) << 6;
    if (t + 1 < NT) {
#pragma unroll
      for (int c = 0; c < 4; ++c) GLDS16(sA[c] + ko, lds + wb + c * 4096 + dW);
#pragma unroll
      for (int c = 0; c < 2; ++c) {
        GLDS16(sK[c] + ko, lds + wb + 16384 + c * 4096 + dW);
        GLDS16(sV[c] + ko, lds + wb + 24576 + c * 4096 + dW);
      }
      if (stageSW) GLDS16(sS + ko, lds + wb + 32768 + dW);
    }

    // ---- kk = 0: 32 MFMA
    bf16x8 a[4], bk[4], bv[4], sw;
#pragma unroll
    for (int mi = 0; mi < 4; ++mi) a[mi] = *(const bf16x8*)(lds + rb + (arow + mi * 16) * 64 + u0);
#pragma unroll
    for (int ni = 0; ni < 4; ++ni) {
      bk[ni] = *(const bf16x8*)(lds + rb + 16384 + (brow + ni * 16) * 64 + u0);
      bv[ni] = *(const bf16x8*)(lds + rb + 24576 + (brow + ni * 16) * 64 + u0);
    }
    if (side) sw = *(const bf16x8*)(lds + rb + 32768 + srow * 64 + u0);
    LGK0;
    __builtin_amdgcn_s_setprio(1);
#pragma unroll
    for (int mi = 0; mi < 4; ++mi)
#pragma unroll
      for (int ni = 0; ni < 4; ++ni) {
        ck[mi][ni] = MFMA16(a[mi], bk[ni], ck[mi][ni]);
        cv[mi][ni] = MFMA16(a[mi], bv[ni], cv[mi][ni]);
      }
    if (side) {
#pragma unroll
      for (int mi = 0; mi < 4; ++mi) qa[mi] = MFMA16(a[mi], sw, qa[mi]);
    }
    __builtin_amdgcn_s_setprio(0);

    // ---- kk = 1: 32 MFMA
#pragma unroll
    for (int mi = 0; mi < 4; ++mi) a[mi] = *(const bf16x8*)(lds + rb + (arow + mi * 16) * 64 + u1);
#pragma unroll
    for (int ni = 0; ni < 4; ++ni) {
      bk[ni] = *(const bf16x8*)(lds + rb + 16384 + (brow + ni * 16) * 64 + u1);
      bv[ni] = *(const bf16x8*)(lds + rb + 24576 + (brow + ni * 16) * 64 + u1);
    }
    if (side) sw = *(const bf16x8*)(lds + rb + 32768 + srow * 64 + u1);
    LGK0;
    __builtin_amdgcn_s_setprio(1);
#pragma unroll
    for (int mi = 0; mi < 4; ++mi)
#pragma unroll
      for (int ni = 0; ni < 4; ++ni) {
        ck[mi][ni] = MFMA16(a[mi], bk[ni], ck[mi][ni]);
        cv[mi][ni] = MFMA16(a[mi], bv[ni], cv[mi][ni]);
      }
    if (side) {
#pragma unroll
      for (int mi = 0; mi < 4; ++mi) qa[mi] = MFMA16(a[mi], sw, qa[mi]);
    }
    __builtin_amdgcn_s_setprio(0);

    asm volatile("s_waitcnt vmcnt(0)" ::: "memory");  // free: issued ~2500 cyc ago
    PH_BAR;
  }

  // epilogue: dots = per-head sum over 64 cols of ck*cv
  float part[4][4];
#pragma unroll
  for (int mi = 0; mi < 4; ++mi)
#pragma unroll
    for (int q = 0; q < 4; ++q) {
      float s = 0.f;
#pragma unroll
      for (int ni = 0; ni < 4; ++ni) s += ck[mi][ni][q] * cv[mi][ni][q];
      part[mi][q] = s;
    }
#pragma unroll
  for (int r = 0; r < 4; ++r) {
#pragma unroll
    for (int mi = 0; mi < 4; ++mi)
#pragma unroll
      for (int q = 0; q < 4; ++q)
        part[mi][q] += __shfl_xor(part[mi][q], 1 << r, 64);
  }
  int h = bx * 2 + wcN;
  if (fr == 0) {
#pragma unroll
    for (int mi = 0; mi < 4; ++mi)
#pragma unroll
      for (int q = 0; q < 4; ++q)
        dotsT[(size_t)h * 16384 + row0 + wrM * 64 + mi * 16 + fg * 4 + q] = part[mi][q];
  }
  if (side) {
    float* dst = (wcN == 0) ? qsumT : dotbT;   // C/D col (lane&15) == side-head index
#pragma unroll
    for (int mi = 0; mi < 4; ++mi)
#pragma unroll
      for (int q = 0; q < 4; ++q)
        dst[(size_t)fr * 16384 + row0 + wrM * 64 + mi * 16 + fg * 4 + q] = qa[mi][q];
  }
}

// ---------------- cumsum + coef + state ----------------
__global__ void k_cumsum(const float* __restrict__ dotsT, const float* __restrict__ dotbT,
                         const float* __restrict__ qsumT, const float* __restrict__ scal,
                         const float* __restrict__ mask,
                         float* __restrict__ coef, float* __restrict__ state) {
  __shared__ float csum[256];
  int b = blockIdx.x >> 4, h = blockIdx.x & 15;
  int t = threadIdx.x;
  float bqs = scal[h], dbc = scal[16 + h];
  size_t m0 = (size_t)b * 4096;
  const float* dro = dotsT + (size_t)h * 16384 + m0;
  const float* dbo = dotbT + (size_t)h * 16384 + m0;
  const float* qso = qsumT + (size_t)h * 16384 + m0;
  const float* mko = mask + m0;
  float loc[16], run = 0.f;
  int s0 = t * 16;
#pragma unroll
  for (int i = 0; i < 16; ++i) {
    int ii = s0 + i;
    float mk = mko[ii];
    float d = (dro[ii] + dbo[ii] + dbc) * mk * mk;
    run += d;
    loc[i] = run;
  }
  csum[t] = run;
  __syncthreads();
  for (int off = 1; off < 256; off <<= 1) {
    float v = (t >= off) ? csum[t - off] : 0.f;
    __syncthreads();
    csum[t] += v;
    __syncthreads();
  }
  float prefix = csum[t] - run;
#pragma unroll
  for (int i = 0; i < 16; ++i) {
    int ii = s0 + i;
    float cum = prefix + loc[i];
    coef[(m0 + ii) * 16 + h] = cum * (qso[ii] + bqs);
  }
  float total = csum[255];
  float* sp = state + (size_t)(b * 16 + h) * 4096;
  for (int i = t; i < 4096; i += 256) sp[i] = total;
}

// ---------------- output GEMM: out = coef(16384x16) @ WosT(16x1024) + bo ----------------
__global__ __launch_bounds__(256) void k_outgemm(const float* __restrict__ coef,
                                                 const float* __restrict__ WosT,
                                                 const float* __restrict__ bo,
                                                 float* __restrict__ out) {
  int t = threadIdx.x;
  int j0 = t * 4;
  f32x4 w4[16];
#pragma unroll
  for (int hh = 0; hh < 16; ++hh) w4[hh] = *(const f32x4*)&WosT[hh * 1024 + j0];
  f32x4 bov = *(const f32x4*)&bo[j0];
  size_t m0 = (size_t)blockIdx.x * 32;
  for (int mi = 0; mi < 32; ++mi) {
    size_t m = m0 + mi;
    const float* cm = &coef[m * 16];
    f32x4 acc = bov;
#pragma unroll
    for (int hh = 0; hh < 16; ++hh) acc += w4[hh] * cm[hh];
    *(f32x4*)&out[m * 1024 + j0] = acc;
  }
}

extern "C" void kernel_launch(void* const* d_in, const int* in_sizes, int n_in,
                              void* d_out, int out_size, void* d_ws, size_t ws_size,
                              hipStream_t stream) {
  const float* X    = (const float*)d_in[0];
  const float* mask = (const float*)d_in[1];
  const float* Wq   = (const float*)d_in[2];
  const float* bq   = (const float*)d_in[3];
  const float* Wk   = (const float*)d_in[4];
  const float* bk   = (const float*)d_in[5];
  const float* Wv   = (const float*)d_in[6];
  const float* bv   = (const float*)d_in[7];
  const float* Wo   = (const float*)d_in[8];
  const float* bo   = (const float*)d_in[9];
  float* out   = (float*)d_out;
  float* state = out + (size_t)16384 * 1024;

  char* w = (char*)d_ws;
  unsigned short* Xb  = (unsigned short*)w; w += (size_t)16384 * 1024 * 2;
  unsigned short* Wkb = (unsigned short*)w; w += (size_t)1024 * 1024 * 2;
  unsigned short* Wvb = (unsigned short*)w; w += (size_t)1024 * 1024 * 2;
  unsigned short* SWb = (unsigned short*)w; w += (size_t)32 * 1024 * 2;
  float* WosT  = (float*)w; w += (size_t)16 * 1024 * 4;
  float* scal  = (float*)w; w += 256;
  float* dotsT = (float*)w; w += (size_t)16 * 16384 * 4;
  float* qsumT = (float*)w; w += (size_t)16 * 16384 * 4;
  float* dotbT = (float*)w; w += (size_t)16 * 16384 * 4;
  float* coef  = (float*)w; w += (size_t)16384 * 16 * 4;

  (void)hipFuncSetAttribute((const void*)k_dualgemm,
                            hipFuncAttributeMaxDynamicSharedMemorySize, 139264);

  hipLaunchKernelGGL(k_prep,     dim3(10433), dim3(256), 0, stream,
                     X, Xb, Wq, bq, Wk, bk, Wv, bv, Wo, Wkb, Wvb, SWb, WosT, scal);
  hipLaunchKernelGGL(k_dualgemm, dim3(512),  dim3(512), 139264, stream, Xb, Wkb, Wvb, SWb,
                     dotsT, qsumT, dotbT);
  hipLaunchKernelGGL(k_cumsum,   dim3(64),   dim3(256), 0, stream, dotsT, dotbT, qsumT, scal,
                     mask, coef, state);
  hipLaunchKernelGGL(k_outgemm,  dim3(512),  dim3(256), 0, stream, coef, WosT, bo, out);
}